// Round 15
// baseline (66.691 us; speedup 1.0000x reference)
//
#include <hip/hip_runtime.h>
#include <math.h>

namespace {
typedef unsigned short u16;
typedef __attribute__((ext_vector_type(8))) short bf16x8;
typedef __attribute__((ext_vector_type(4))) float f32x4;

constexpr int H  = 8;
constexpr int B  = 4;
constexpr int S  = 1024;
constexpr int M  = 512;
constexpr int D  = 64;
constexpr int BS = B * S;            // 4096 rows
constexpr int NC = 16;               // chunks per sequence
constexpr int CH = 64;               // chunk length
constexpr int QSZ = H * B * S * D;   // 2097152
constexpr int NQKV = 3 * M;          // 1536

__device__ __forceinline__ float elu1(float x) {
  return x > 0.f ? x + 1.f : __expf(x);
}

__device__ __forceinline__ u16 f2bf(float f) {
  unsigned u = __builtin_bit_cast(unsigned, f);
  u += 0x7fffu + ((u >> 16) & 1u);   // RNE
  return (u16)(u >> 16);
}

__device__ __forceinline__ float bf2f(u16 v) {
  return __builtin_bit_cast(float, ((unsigned)v) << 16);
}

__device__ __forceinline__ void gload16(const u16* g, u16* l) {
  __builtin_amdgcn_global_load_lds(
      (const __attribute__((address_space(1))) unsigned int*)g,
      (__attribute__((address_space(3))) unsigned int*)l, 16, 0, 0);
}

// ---------------------------------------------------------------------------
// prep: fused  convert_x (blocks 0..2047) | build_wqkv (2048..2239) |
//              build_wo (2240..2303)
// ---------------------------------------------------------------------------
__global__ __launch_bounds__(256) void prep(
    const float* __restrict__ X, const float* __restrict__ Wq,
    const float* __restrict__ Wk, const float* __restrict__ Wv,
    const float* __restrict__ Wo, u16* __restrict__ Xb,
    u16* __restrict__ WCT, u16* __restrict__ WoT) {
  __shared__ float t[64][65];
  const int bid = blockIdx.x;
  if (bid < 2048) {
    const int i = bid * 256 + threadIdx.x;
    const float4 v = reinterpret_cast<const float4*>(X)[i];
    u16 o[4] = {f2bf(v.x), f2bf(v.y), f2bf(v.z), f2bf(v.w)};
    *reinterpret_cast<uint2*>(Xb + i * 4) = *reinterpret_cast<uint2*>(o);
  } else if (bid < 2240) {
    const int bb = bid - 2048;
    const int mt = bb & 7, ph = bb >> 3;
    const int p = ph >> 3, h = ph & 7;
    const float* W = ((p == 0) ? Wq : (p == 1) ? Wk : Wv) + h * (M * D);
    const int m0 = mt * 64;
#pragma unroll
    for (int j = 0; j < 4; ++j) {
      const int i = j * 256 + threadIdx.x;
      const int mm = i >> 4, dd = (i & 15) * 4;
      const float4 v = *reinterpret_cast<const float4*>(W + (m0 + mm) * D + dd);
      t[mm][dd + 0] = v.x; t[mm][dd + 1] = v.y;
      t[mm][dd + 2] = v.z; t[mm][dd + 3] = v.w;
    }
    __syncthreads();
    const int dd = threadIdx.x >> 2, qr = (threadIdx.x & 3) * 16;
    u16* o = WCT + (p * M + h * D + dd) * M + m0 + qr;
#pragma unroll
    for (int i = 0; i < 16; ++i) o[i] = f2bf(t[qr + i][dd]);
  } else {
    const int bb = bid - 2240;
    const int m0 = (bb & 7) * 64, n0 = (bb >> 3) * 64;
#pragma unroll
    for (int j = 0; j < 4; ++j) {
      const int i = j * 256 + threadIdx.x;
      const int mm = i >> 4, nn = (i & 15) * 4;
      const float4 v = *reinterpret_cast<const float4*>(Wo + (m0 + mm) * M + n0 + nn);
      t[mm][nn + 0] = v.x; t[mm][nn + 1] = v.y;
      t[mm][nn + 2] = v.z; t[mm][nn + 3] = v.w;
    }
    __syncthreads();
    const int nn = threadIdx.x >> 2, qr = (threadIdx.x & 3) * 16;
    u16* o = WoT + (n0 + nn) * M + m0 + qr;
#pragma unroll
    for (int i = 0; i < 16; ++i) o[i] = f2bf(t[qr + i][nn]);
  }
}

// ---------------------------------------------------------------------------
// QKV GEMM: 128x128 tile, BK=32, dbuf prefetch, 8 waves (R12 form).
// ---------------------------------------------------------------------------
__global__ __launch_bounds__(512) void gemm_qkv(const u16* __restrict__ A,
                                                const u16* __restrict__ BT,
                                                u16* __restrict__ qb,
                                                u16* __restrict__ kb,
                                                u16* __restrict__ kTb,
                                                u16* __restrict__ vTb) {
  __shared__ alignas(16) u16 As[2][4096];
  __shared__ alignas(16) u16 Bs[2][4096];
  const int tid = threadIdx.x;
  const int wave = tid >> 6, lane = tid & 63;
  const int r0 = blockIdx.x * 128, c0 = blockIdx.y * 128;
  const int wr = (wave >> 1) * 32, wc = (wave & 1) * 64;
  const int l15 = lane & 15, lk = lane >> 4;

  f32x4 acc[2][4] = {};
  const u16* gA = A + (size_t)(r0 + wave * 16 + (lane >> 2)) * 512 + (lane & 3) * 8;
  const u16* gB = BT + (size_t)(c0 + wave * 16 + (lane >> 2)) * 512 + (lane & 3) * 8;

#define STG_QKV(kt, b)                          \
  {                                             \
    const int ko = (kt) * 32;                   \
    gload16(gA + ko, &As[b][wave * 512]);       \
    gload16(gB + ko, &Bs[b][wave * 512]);       \
  }

  STG_QKV(0, 0);
  __syncthreads();
  for (int kt = 0; kt < 16; ++kt) {
    if (kt < 15) STG_QKV(kt + 1, (kt + 1) & 1);
    const bf16x8* As8 = reinterpret_cast<const bf16x8*>(As[kt & 1]);
    const bf16x8* Bs8 = reinterpret_cast<const bf16x8*>(Bs[kt & 1]);
    bf16x8 af[2], bff[4];
#pragma unroll
    for (int mf = 0; mf < 2; ++mf)
      af[mf] = As8[(wr + mf * 16 + l15) * 4 + lk];
#pragma unroll
    for (int nf = 0; nf < 4; ++nf)
      bff[nf] = Bs8[(wc + nf * 16 + l15) * 4 + lk];
#pragma unroll
    for (int mf = 0; mf < 2; ++mf)
#pragma unroll
      for (int nf = 0; nf < 4; ++nf)
        acc[mf][nf] = __builtin_amdgcn_mfma_f32_16x16x32_bf16(
            af[mf], bff[nf], acc[mf][nf], 0, 0, 0);
    __syncthreads();
  }
#undef STG_QKV

#pragma unroll
  for (int nf = 0; nf < 4; ++nf) {
    const int col = c0 + wc + nf * 16 + l15;
    const int p = col >> 9, hh = (col >> 6) & 7, dd = col & 63;
#pragma unroll
    for (int mf = 0; mf < 2; ++mf) {
      const int rowb = r0 + wr + mf * 16 + lk * 4;
      const int b = rowb >> 10, s = rowb & 1023;
      const int hb = hh * B + b;
      u16 ov[4];
#pragma unroll
      for (int r = 0; r < 4; ++r) {
        float v = acc[mf][nf][r];
        if (p < 2) v = elu1(v);
        ov[r] = f2bf(v);
      }
      if (p == 0) {
#pragma unroll
        for (int r = 0; r < 4; ++r)
          qb[((size_t)(hb << 10) + s + r) * 64 + dd] = ov[r];
      } else if (p == 1) {
#pragma unroll
        for (int r = 0; r < 4; ++r)
          kb[((size_t)(hb << 10) + s + r) * 64 + dd] = ov[r];
        *reinterpret_cast<uint2*>(kTb + ((size_t)(hb * 64 + dd) << 10) + s) =
            *reinterpret_cast<uint2*>(ov);
      } else {
        *reinterpret_cast<uint2*>(vTb + ((size_t)(hb * 64 + dd) << 10) + s) =
            *reinterpret_cast<uint2*>(ov);
      }
    }
  }
}

// ---------------------------------------------------------------------------
// Output GEMM: 128x64 tile, BK=32, dbuf prefetch, 8 waves (R12 form).
// ---------------------------------------------------------------------------
__global__ __launch_bounds__(512) void gemm_out(const u16* __restrict__ A,
                                                const u16* __restrict__ BT,
                                                float* __restrict__ out) {
  __shared__ alignas(16) u16 As[2][4096];
  __shared__ alignas(16) u16 Bs[2][2048];
  const int tid = threadIdx.x;
  const int wave = tid >> 6, lane = tid & 63;
  const int r0 = blockIdx.x * 128, c0 = blockIdx.y * 64;
  const int wr = (wave >> 1) * 32, wc = (wave & 1) * 32;
  const int l15 = lane & 15, lk = lane >> 4;

  f32x4 acc[2][2] = {};
  const u16* gA = A + (size_t)(r0 + wave * 16 + (lane >> 2)) * 512 + (lane & 3) * 8;
  const u16* gB = BT + (size_t)(c0 + (wave - 4) * 16 + (lane >> 2)) * 512 + (lane & 3) * 8;

#define STG_OUT(kt, b)                                        \
  {                                                           \
    const int ko = (kt) * 32;                                 \
    gload16(gA + ko, &As[b][wave * 512]);                     \
    if (wave >= 4) gload16(gB + ko, &Bs[b][(wave - 4) * 512]); \
  }

  STG_OUT(0, 0);
  __syncthreads();
  for (int kt = 0; kt < 16; ++kt) {
    if (kt < 15) STG_OUT(kt + 1, (kt + 1) & 1);
    const bf16x8* As8 = reinterpret_cast<const bf16x8*>(As[kt & 1]);
    const bf16x8* Bs8 = reinterpret_cast<const bf16x8*>(Bs[kt & 1]);
    bf16x8 a[2], b[2];
#pragma unroll
    for (int mf = 0; mf < 2; ++mf)
      a[mf] = As8[(wr + mf * 16 + l15) * 4 + lk];
#pragma unroll
    for (int nf = 0; nf < 2; ++nf)
      b[nf] = Bs8[(wc + nf * 16 + l15) * 4 + lk];
#pragma unroll
    for (int mf = 0; mf < 2; ++mf)
#pragma unroll
      for (int nf = 0; nf < 2; ++nf)
        acc[mf][nf] = __builtin_amdgcn_mfma_f32_16x16x32_bf16(
            a[mf], b[nf], acc[mf][nf], 0, 0, 0);
    __syncthreads();
  }
#undef STG_OUT

#pragma unroll
  for (int nf = 0; nf < 2; ++nf) {
    const int col = c0 + wc + nf * 16 + l15;
#pragma unroll
    for (int mf = 0; mf < 2; ++mf)
#pragma unroll
      for (int r = 0; r < 4; ++r) {
        const int row = r0 + wr + mf * 16 + lk * 4 + r;
        out[(size_t)row * M + col] = acc[mf][nf][r];
      }
  }
}

// ---------------------------------------------------------------------------
// Chunk Gram state via MFMA (R6 verbatim).
// ---------------------------------------------------------------------------
__global__ __launch_bounds__(256) void chunkstate_mfma(
    const u16* __restrict__ kTb, const u16* __restrict__ vTb,
    float* __restrict__ G32, float* __restrict__ Ks) {
  const int tid = threadIdx.x, wave = tid >> 6, lane = tid & 63;
  const int bx = blockIdx.x, hb = bx >> 4, cc = bx & 15, s0 = cc * CH;
  const u16* vbase = vTb + ((size_t)hb * 64) * 1024 + s0;
  const u16* kbase = kTb + ((size_t)hb * 64) * 1024 + s0;

  bf16x8 av[2];
#pragma unroll
  for (int ks = 0; ks < 2; ++ks)
    av[ks] = *reinterpret_cast<const bf16x8*>(
        vbase + (size_t)(wave * 16 + (lane & 15)) * 1024 + ks * 32 + (lane >> 4) * 8);

  f32x4 acc[4] = {};
#pragma unroll
  for (int fd = 0; fd < 4; ++fd)
#pragma unroll
    for (int ks = 0; ks < 2; ++ks) {
      bf16x8 bk = *reinterpret_cast<const bf16x8*>(
          kbase + (size_t)(fd * 16 + (lane & 15)) * 1024 + ks * 32 + (lane >> 4) * 8);
      acc[fd] = __builtin_amdgcn_mfma_f32_16x16x32_bf16(av[ks], bk, acc[fd], 0, 0, 0);
    }

  float* Gp = G32 + (size_t)bx * 4096;
#pragma unroll
  for (int fd = 0; fd < 4; ++fd)
#pragma unroll
    for (int r = 0; r < 4; ++r) {
      const int e = wave * 16 + (lane >> 4) * 4 + r;
      const int d = fd * 16 + (lane & 15);
      Gp[e * 64 + d] = acc[fd][r];
    }

  const int d = tid >> 2, tq = tid & 3;
  const u16* kp = kbase + (size_t)d * 1024 + tq * 16;
  float ks = 0.f;
#pragma unroll
  for (int j = 0; j < 16; ++j) ks += bf2f(kp[j]);
  ks += __shfl_xor(ks, 1);
  ks += __shfl_xor(ks, 2);
  if (tq == 0) Ks[bx * 64 + d] = ks;
}

// ---------------------------------------------------------------------------
// Exclusive prefix over chunks (R6 verbatim).
// ---------------------------------------------------------------------------
__global__ __launch_bounds__(256) void prefix_kernel(
    const float* __restrict__ G32, u16* __restrict__ GTb,
    float* __restrict__ Ks) {
  const int hb = blockIdx.x, eg = blockIdx.y;
  const int tid = threadIdx.x;
  const int e = eg * 4 + (tid >> 6), d = tid & 63;
  const size_t base = ((size_t)(hb * 16) * 64 + e) * 64 + d;
  float acc = 0.f;
#pragma unroll
  for (int c = 0; c < 16; ++c) {
    const float v = G32[base + (size_t)c * 4096];
    GTb[base + (size_t)c * 4096] = f2bf(acc);
    acc += v;
  }
  if (eg == 0 && tid < 64) {
    float ka = 0.f;
#pragma unroll
    for (int c = 0; c < 16; ++c) {
      const int idx = (hb * 16 + c) * 64 + tid;
      const float v = Ks[idx];
      Ks[idx] = ka;
      ka += v;
    }
  }
}

// ---------------------------------------------------------------------------
// Chunk output via MFMA (R6 verbatim).
// ---------------------------------------------------------------------------
__global__ __launch_bounds__(256) void chunkout_mfma(
    const u16* __restrict__ qb, const u16* __restrict__ kb,
    const u16* __restrict__ vTb, const u16* __restrict__ GTb,
    const float* __restrict__ Kc, u16* __restrict__ att) {
  __shared__ alignas(16) u16 Qs[4096], Kls[4096], Vs[4096], Gs[4096], Astg[4096];
  const int tid = threadIdx.x, wave = tid >> 6, lane = tid & 63;
  const int bx = blockIdx.x, hb = bx >> 4, cc = bx & 15, s0 = cc * CH;
  const int h = hb >> 2, b = hb & 3;

  {
    const u16* qg = qb + ((size_t)(hb << 10) + s0) * 64;
    const u16* kg = kb + ((size_t)(hb << 10) + s0) * 64;
    const u16* gg = GTb + (size_t)bx * 4096;
#pragma unroll
    for (int j = 0; j < 2; ++j) {
      const int off = j * 2048 + wave * 512;
      gload16(qg + off + lane * 8, Qs + off);
      gload16(kg + off + lane * 8, Kls + off);
      gload16(gg + off + lane * 8, Gs + off);
    }
    const u16* vg = vTb + ((size_t)hb * 64) * 1024 + s0;
#pragma unroll
    for (int j = 0; j < 2; ++j) {
      const int e0 = j * 32 + wave * 8;
      gload16(vg + (size_t)(e0 + (lane >> 3)) * 1024 + (lane & 7) * 8,
              Vs + e0 * 64);
    }
  }
  __syncthreads();

  const bf16x8* Qs8 = reinterpret_cast<const bf16x8*>(Qs);
  const bf16x8* Ks8 = reinterpret_cast<const bf16x8*>(Kls);
  const bf16x8* Vs8 = reinterpret_cast<const bf16x8*>(Vs);
  const bf16x8* Gs8 = reinterpret_cast<const bf16x8*>(Gs);
  const bf16x8* As8 = reinterpret_cast<const bf16x8*>(Astg);

  const int i0 = wave * 16;
  const int l15 = lane & 15, lk = lane >> 4;

  bf16x8 aq[2];
#pragma unroll
  for (int ks = 0; ks < 2; ++ks)
    aq[ks] = Qs8[(i0 + l15) * 8 + ks * 4 + lk];

  f32x4 a[4] = {};
#pragma unroll
  for (int fj = 0; fj < 4; ++fj)
#pragma unroll
    for (int ks = 0; ks < 2; ++ks) {
      bf16x8 bk = Ks8[(fj * 16 + l15) * 8 + ks * 4 + lk];
      a[fj] = __builtin_amdgcn_mfma_f32_16x16x32_bf16(aq[ks], bk, a[fj], 0, 0, 0);
    }

  const float4 kc4 = *reinterpret_cast<const float4*>(Kc + bx * 64 + l15 * 4);
  float z[4];
  const int rbase = lk * 4;
#pragma unroll
  for (int r = 0; r < 4; ++r) {
    const int il = rbase + r;
    float sum = 0.f;
#pragma unroll
    for (int fj = 0; fj < 4; ++fj) {
      const int j = fj * 16 + l15;
      if (j > i0 + il) a[fj][r] = 0.f;
      sum += a[fj][r];
    }
    const uint2 qrow = *reinterpret_cast<const uint2*>(Qs + (i0 + il) * 64 + l15 * 4);
    const u16* qr16 = reinterpret_cast<const u16*>(&qrow);
    sum += bf2f(qr16[0]) * kc4.x + bf2f(qr16[1]) * kc4.y +
           bf2f(qr16[2]) * kc4.z + bf2f(qr16[3]) * kc4.w;
    z[r] = sum;
  }
#pragma unroll
  for (int off = 1; off <= 8; off <<= 1)
#pragma unroll
    for (int r = 0; r < 4; ++r) z[r] += __shfl_xor(z[r], off);

#pragma unroll
  for (int fj = 0; fj < 4; ++fj)
#pragma unroll
    for (int r = 0; r < 4; ++r)
      Astg[(i0 + rbase + r) * 64 + fj * 16 + l15] = f2bf(a[fj][r]);
  // no barrier: each wave reads only its own 16-row Astg block

  f32x4 o[4] = {};
#pragma unroll
  for (int fe = 0; fe < 4; ++fe) {
#pragma unroll
    for (int ks = 0; ks < 2; ++ks) {
      bf16x8 bg = Gs8[(fe * 16 + l15) * 8 + ks * 4 + lk];
      o[fe] = __builtin_amdgcn_mfma_f32_16x16x32_bf16(aq[ks], bg, o[fe], 0, 0, 0);
    }
#pragma unroll
    for (int ks = 0; ks < 2; ++ks) {
      bf16x8 aa = As8[(i0 + l15) * 8 + ks * 4 + lk];
      bf16x8 bv = Vs8[(fe * 16 + l15) * 8 + ks * 4 + lk];
      o[fe] = __builtin_amdgcn_mfma_f32_16x16x32_bf16(aa, bv, o[fe], 0, 0, 0);
    }
  }

  float rz[4];
#pragma unroll
  for (int r = 0; r < 4; ++r) rz[r] = 1.f / z[r];
#pragma unroll
  for (int fe = 0; fe < 4; ++fe)
#pragma unroll
    for (int r = 0; r < 4; ++r) {
      const int srow = s0 + i0 + rbase + r;
      att[((size_t)(b << 10) + srow) * 512 + h * 64 + fe * 16 + l15] =
          f2bf(o[fe][r] * rz[r]);
    }
}

}  // namespace

extern "C" void kernel_launch(void* const* d_in, const int* in_sizes, int n_in,
                              void* d_out, int out_size, void* d_ws,
                              size_t ws_size, hipStream_t stream) {
  const float* X  = (const float*)d_in[0];
  const float* Wq = (const float*)d_in[2];
  const float* Wk = (const float*)d_in[3];
  const float* Wv = (const float*)d_in[4];
  const float* Wo = (const float*)d_in[5];
  float* out = (float*)d_out;

  u16* Xb  = (u16*)d_ws;            // QSZ u16
  u16* att = Xb;                    // alias: written after Xb fully consumed
  u16* WCT = Xb + QSZ;              // 1536*512
  u16* WoT = WCT + NQKV * M;        // 512*512
  u16* qb  = WoT + M * M;           // QSZ each
  u16* kb  = qb + QSZ;
  u16* kTb = kb + QSZ;
  u16* vTb = kTb + QSZ;
  u16* GTb = vTb + QSZ;             // QSZ
  float* G32 = (float*)(GTb + QSZ); // QSZ fp32
  float* Ks  = G32 + QSZ;           // 32768 fp32

  prep<<<dim3(2304), 256, 0, stream>>>(X, Wq, Wk, Wv, Wo, Xb, WCT, WoT);
  gemm_qkv<<<dim3(BS / 128, NQKV / 128), 512, 0, stream>>>(Xb, WCT, qb, kb,
                                                           kTb, vTb);
  // MEASUREMENT: idempotent duplicate launch — dur_us delta vs R12 == t_qkv.
  gemm_qkv<<<dim3(BS / 128, NQKV / 128), 512, 0, stream>>>(Xb, WCT, qb, kb,
                                                           kTb, vTb);
  chunkstate_mfma<<<dim3(H * B * NC), 256, 0, stream>>>(kTb, vTb, G32, Ks);
  prefix_kernel<<<dim3(H * B, 16), 256, 0, stream>>>(G32, GTb, Ks);
  chunkout_mfma<<<dim3(H * B * NC), 256, 0, stream>>>(qb, kb, vTb, GTb, Ks,
                                                      att);
  gemm_out<<<dim3(BS / 128, M / 64), 512, 0, stream>>>(att, WoT, out);
}

// Round 16
// 63.977 us; speedup vs baseline: 1.0424x; 1.0424x over previous
//
#include <hip/hip_runtime.h>
#include <math.h>

namespace {
typedef unsigned short u16;
typedef __attribute__((ext_vector_type(8))) short bf16x8;
typedef __attribute__((ext_vector_type(4))) float f32x4;

constexpr int H  = 8;
constexpr int B  = 4;
constexpr int S  = 1024;
constexpr int M  = 512;
constexpr int D  = 64;
constexpr int BS = B * S;            // 4096 rows
constexpr int NC = 16;               // chunks per sequence
constexpr int CH = 64;               // chunk length
constexpr int QSZ = H * B * S * D;   // 2097152
constexpr int NQKV = 3 * M;          // 1536

__device__ __forceinline__ float elu1(float x) {
  return x > 0.f ? x + 1.f : __expf(x);
}

__device__ __forceinline__ u16 f2bf(float f) {
  unsigned u = __builtin_bit_cast(unsigned, f);
  u += 0x7fffu + ((u >> 16) & 1u);   // RNE
  return (u16)(u >> 16);
}

__device__ __forceinline__ float bf2f(u16 v) {
  return __builtin_bit_cast(float, ((unsigned)v) << 16);
}

__device__ __forceinline__ void gload16(const u16* g, u16* l) {
  __builtin_amdgcn_global_load_lds(
      (const __attribute__((address_space(1))) unsigned int*)g,
      (__attribute__((address_space(3))) unsigned int*)l, 16, 0, 0);
}

// ---------------------------------------------------------------------------
// prep: fused  convert_x (blocks 0..2047) | build_wqkv (2048..2239) |
//              build_wo (2240..2303)
// ---------------------------------------------------------------------------
__global__ __launch_bounds__(256) void prep(
    const float* __restrict__ X, const float* __restrict__ Wq,
    const float* __restrict__ Wk, const float* __restrict__ Wv,
    const float* __restrict__ Wo, u16* __restrict__ Xb,
    u16* __restrict__ WCT, u16* __restrict__ WoT) {
  __shared__ float t[64][65];
  const int bid = blockIdx.x;
  if (bid < 2048) {
    const int i = bid * 256 + threadIdx.x;
    const float4 v = reinterpret_cast<const float4*>(X)[i];
    u16 o[4] = {f2bf(v.x), f2bf(v.y), f2bf(v.z), f2bf(v.w)};
    *reinterpret_cast<uint2*>(Xb + i * 4) = *reinterpret_cast<uint2*>(o);
  } else if (bid < 2240) {
    const int bb = bid - 2048;
    const int mt = bb & 7, ph = bb >> 3;
    const int p = ph >> 3, h = ph & 7;
    const float* W = ((p == 0) ? Wq : (p == 1) ? Wk : Wv) + h * (M * D);
    const int m0 = mt * 64;
#pragma unroll
    for (int j = 0; j < 4; ++j) {
      const int i = j * 256 + threadIdx.x;
      const int mm = i >> 4, dd = (i & 15) * 4;
      const float4 v = *reinterpret_cast<const float4*>(W + (m0 + mm) * D + dd);
      t[mm][dd + 0] = v.x; t[mm][dd + 1] = v.y;
      t[mm][dd + 2] = v.z; t[mm][dd + 3] = v.w;
    }
    __syncthreads();
    const int dd = threadIdx.x >> 2, qr = (threadIdx.x & 3) * 16;
    u16* o = WCT + (p * M + h * D + dd) * M + m0 + qr;
#pragma unroll
    for (int i = 0; i < 16; ++i) o[i] = f2bf(t[qr + i][dd]);
  } else {
    const int bb = bid - 2240;
    const int m0 = (bb & 7) * 64, n0 = (bb >> 3) * 64;
#pragma unroll
    for (int j = 0; j < 4; ++j) {
      const int i = j * 256 + threadIdx.x;
      const int mm = i >> 4, nn = (i & 15) * 4;
      const float4 v = *reinterpret_cast<const float4*>(Wo + (m0 + mm) * M + n0 + nn);
      t[mm][nn + 0] = v.x; t[mm][nn + 1] = v.y;
      t[mm][nn + 2] = v.z; t[mm][nn + 3] = v.w;
    }
    __syncthreads();
    const int nn = threadIdx.x >> 2, qr = (threadIdx.x & 3) * 16;
    u16* o = WoT + (n0 + nn) * M + m0 + qr;
#pragma unroll
    for (int i = 0; i < 16; ++i) o[i] = f2bf(t[qr + i][nn]);
  }
}

// ---------------------------------------------------------------------------
// QKV GEMM: 128x128 tile, BK=32, dbuf prefetch, 8 waves (R12 form).
// ---------------------------------------------------------------------------
__global__ __launch_bounds__(512) void gemm_qkv(const u16* __restrict__ A,
                                                const u16* __restrict__ BT,
                                                u16* __restrict__ qb,
                                                u16* __restrict__ kb,
                                                u16* __restrict__ kTb,
                                                u16* __restrict__ vTb) {
  __shared__ alignas(16) u16 As[2][4096];
  __shared__ alignas(16) u16 Bs[2][4096];
  const int tid = threadIdx.x;
  const int wave = tid >> 6, lane = tid & 63;
  const int r0 = blockIdx.x * 128, c0 = blockIdx.y * 128;
  const int wr = (wave >> 1) * 32, wc = (wave & 1) * 64;
  const int l15 = lane & 15, lk = lane >> 4;

  f32x4 acc[2][4] = {};
  const u16* gA = A + (size_t)(r0 + wave * 16 + (lane >> 2)) * 512 + (lane & 3) * 8;
  const u16* gB = BT + (size_t)(c0 + wave * 16 + (lane >> 2)) * 512 + (lane & 3) * 8;

#define STG_QKV(kt, b)                          \
  {                                             \
    const int ko = (kt) * 32;                   \
    gload16(gA + ko, &As[b][wave * 512]);       \
    gload16(gB + ko, &Bs[b][wave * 512]);       \
  }

  STG_QKV(0, 0);
  __syncthreads();
  for (int kt = 0; kt < 16; ++kt) {
    if (kt < 15) STG_QKV(kt + 1, (kt + 1) & 1);
    const bf16x8* As8 = reinterpret_cast<const bf16x8*>(As[kt & 1]);
    const bf16x8* Bs8 = reinterpret_cast<const bf16x8*>(Bs[kt & 1]);
    bf16x8 af[2], bff[4];
#pragma unroll
    for (int mf = 0; mf < 2; ++mf)
      af[mf] = As8[(wr + mf * 16 + l15) * 4 + lk];
#pragma unroll
    for (int nf = 0; nf < 4; ++nf)
      bff[nf] = Bs8[(wc + nf * 16 + l15) * 4 + lk];
#pragma unroll
    for (int mf = 0; mf < 2; ++mf)
#pragma unroll
      for (int nf = 0; nf < 4; ++nf)
        acc[mf][nf] = __builtin_amdgcn_mfma_f32_16x16x32_bf16(
            af[mf], bff[nf], acc[mf][nf], 0, 0, 0);
    __syncthreads();
  }
#undef STG_QKV

#pragma unroll
  for (int nf = 0; nf < 4; ++nf) {
    const int col = c0 + wc + nf * 16 + l15;
    const int p = col >> 9, hh = (col >> 6) & 7, dd = col & 63;
#pragma unroll
    for (int mf = 0; mf < 2; ++mf) {
      const int rowb = r0 + wr + mf * 16 + lk * 4;
      const int b = rowb >> 10, s = rowb & 1023;
      const int hb = hh * B + b;
      u16 ov[4];
#pragma unroll
      for (int r = 0; r < 4; ++r) {
        float v = acc[mf][nf][r];
        if (p < 2) v = elu1(v);
        ov[r] = f2bf(v);
      }
      if (p == 0) {
#pragma unroll
        for (int r = 0; r < 4; ++r)
          qb[((size_t)(hb << 10) + s + r) * 64 + dd] = ov[r];
      } else if (p == 1) {
#pragma unroll
        for (int r = 0; r < 4; ++r)
          kb[((size_t)(hb << 10) + s + r) * 64 + dd] = ov[r];
        *reinterpret_cast<uint2*>(kTb + ((size_t)(hb * 64 + dd) << 10) + s) =
            *reinterpret_cast<uint2*>(ov);
      } else {
        *reinterpret_cast<uint2*>(vTb + ((size_t)(hb * 64 + dd) << 10) + s) =
            *reinterpret_cast<uint2*>(ov);
      }
    }
  }
}

// ---------------------------------------------------------------------------
// Output GEMM: 128x64 tile, BK=32, dbuf prefetch, 8 waves (R12 form).
// ---------------------------------------------------------------------------
__global__ __launch_bounds__(512) void gemm_out(const u16* __restrict__ A,
                                                const u16* __restrict__ BT,
                                                float* __restrict__ out) {
  __shared__ alignas(16) u16 As[2][4096];
  __shared__ alignas(16) u16 Bs[2][2048];
  const int tid = threadIdx.x;
  const int wave = tid >> 6, lane = tid & 63;
  const int r0 = blockIdx.x * 128, c0 = blockIdx.y * 64;
  const int wr = (wave >> 1) * 32, wc = (wave & 1) * 32;
  const int l15 = lane & 15, lk = lane >> 4;

  f32x4 acc[2][2] = {};
  const u16* gA = A + (size_t)(r0 + wave * 16 + (lane >> 2)) * 512 + (lane & 3) * 8;
  const u16* gB = BT + (size_t)(c0 + (wave - 4) * 16 + (lane >> 2)) * 512 + (lane & 3) * 8;

#define STG_OUT(kt, b)                                        \
  {                                                           \
    const int ko = (kt) * 32;                                 \
    gload16(gA + ko, &As[b][wave * 512]);                     \
    if (wave >= 4) gload16(gB + ko, &Bs[b][(wave - 4) * 512]); \
  }

  STG_OUT(0, 0);
  __syncthreads();
  for (int kt = 0; kt < 16; ++kt) {
    if (kt < 15) STG_OUT(kt + 1, (kt + 1) & 1);
    const bf16x8* As8 = reinterpret_cast<const bf16x8*>(As[kt & 1]);
    const bf16x8* Bs8 = reinterpret_cast<const bf16x8*>(Bs[kt & 1]);
    bf16x8 a[2], b[2];
#pragma unroll
    for (int mf = 0; mf < 2; ++mf)
      a[mf] = As8[(wr + mf * 16 + l15) * 4 + lk];
#pragma unroll
    for (int nf = 0; nf < 2; ++nf)
      b[nf] = Bs8[(wc + nf * 16 + l15) * 4 + lk];
#pragma unroll
    for (int mf = 0; mf < 2; ++mf)
#pragma unroll
      for (int nf = 0; nf < 2; ++nf)
        acc[mf][nf] = __builtin_amdgcn_mfma_f32_16x16x32_bf16(
            a[mf], b[nf], acc[mf][nf], 0, 0, 0);
    __syncthreads();
  }
#undef STG_OUT

#pragma unroll
  for (int nf = 0; nf < 2; ++nf) {
    const int col = c0 + wc + nf * 16 + l15;
#pragma unroll
    for (int mf = 0; mf < 2; ++mf)
#pragma unroll
      for (int r = 0; r < 4; ++r) {
        const int row = r0 + wr + mf * 16 + lk * 4 + r;
        out[(size_t)row * M + col] = acc[mf][nf][r];
      }
  }
}

// ---------------------------------------------------------------------------
// stateprefix: chunkstate + prefix fused, one block per hb (NO cross-block
// deps). Phase A: 4 waves x 4 chunks each compute G_c = V_c^T K_c via MFMA,
// storing bf16 G in LDS (16 x 8KB = 128KB) + raw ksums in LDS. Phase B
// (after __syncthreads): block-local exclusive prefix -> GTb (bf16) and
// Ks (fp32) in global, identical layout to the old prefix_kernel outputs.
// Eliminates the 16MB G32 global roundtrip and one dispatch gap.
// ---------------------------------------------------------------------------
__global__ __launch_bounds__(256) void stateprefix(
    const u16* __restrict__ kTb, const u16* __restrict__ vTb,
    u16* __restrict__ GTb, float* __restrict__ Ks) {
  __shared__ u16 Gl[NC * 4096];      // 128KB: per-chunk bf16 G
  __shared__ float Kss[NC * 64];     // 4KB: per-chunk raw ksums
  const int tid = threadIdx.x, wave = tid >> 6, lane = tid & 63;
  const int hb = blockIdx.x;
  const int l15 = lane & 15, lk = lane >> 4;
  const u16* vbase = vTb + ((size_t)hb * 64) * 1024;
  const u16* kbase = kTb + ((size_t)hb * 64) * 1024;

  // ---- phase A: per-chunk Gram states ----
  for (int i = 0; i < 4; ++i) {
    const int c = wave * 4 + i, s0 = c * 64;
    bf16x8 bk[4][2];
#pragma unroll
    for (int fd = 0; fd < 4; ++fd)
#pragma unroll
      for (int ks = 0; ks < 2; ++ks)
        bk[fd][ks] = *reinterpret_cast<const bf16x8*>(
            kbase + (size_t)(fd * 16 + l15) * 1024 + s0 + ks * 32 + lk * 8);
#pragma unroll
    for (int eg = 0; eg < 4; ++eg) {
      bf16x8 av[2];
#pragma unroll
      for (int ks = 0; ks < 2; ++ks)
        av[ks] = *reinterpret_cast<const bf16x8*>(
            vbase + (size_t)(eg * 16 + l15) * 1024 + s0 + ks * 32 + lk * 8);
      f32x4 acc[4] = {};
#pragma unroll
      for (int fd = 0; fd < 4; ++fd)
#pragma unroll
        for (int ks = 0; ks < 2; ++ks)
          acc[fd] = __builtin_amdgcn_mfma_f32_16x16x32_bf16(av[ks], bk[fd][ks],
                                                           acc[fd], 0, 0, 0);
#pragma unroll
      for (int fd = 0; fd < 4; ++fd)
#pragma unroll
        for (int r = 0; r < 4; ++r)
          Gl[c * 4096 + (eg * 16 + lk * 4 + r) * 64 + fd * 16 + l15] =
              f2bf(acc[fd][r]);
    }
    // ksum: lane owns column d = lane
    float ksum = 0.f;
#pragma unroll
    for (int j = 0; j < 8; ++j) {
      const bf16x8 kv = *reinterpret_cast<const bf16x8*>(
          kbase + (size_t)lane * 1024 + s0 + j * 8);
#pragma unroll
      for (int e = 0; e < 8; ++e) ksum += bf2f((u16)kv[e]);
    }
    Kss[c * 64 + lane] = ksum;
  }
  __syncthreads();

  // ---- phase B: block-local exclusive prefix ----
#pragma unroll
  for (int j = 0; j < 16; ++j) {
    const int pos = j * 256 + tid;
    float facc = 0.f;
#pragma unroll
    for (int c = 0; c < NC; ++c) {
      const float v = bf2f(Gl[c * 4096 + pos]);
      GTb[((size_t)(hb * NC) + c) * 4096 + pos] = f2bf(facc);
      facc += v;
    }
  }
  if (tid < 64) {
    float ka = 0.f;
#pragma unroll
    for (int c = 0; c < NC; ++c) {
      Ks[(hb * NC + c) * 64 + tid] = ka;
      ka += Kss[c * 64 + tid];
    }
  }
}

// ---------------------------------------------------------------------------
// Chunk output via MFMA (R6 verbatim).
// ---------------------------------------------------------------------------
__global__ __launch_bounds__(256) void chunkout_mfma(
    const u16* __restrict__ qb, const u16* __restrict__ kb,
    const u16* __restrict__ vTb, const u16* __restrict__ GTb,
    const float* __restrict__ Kc, u16* __restrict__ att) {
  __shared__ alignas(16) u16 Qs[4096], Kls[4096], Vs[4096], Gs[4096], Astg[4096];
  const int tid = threadIdx.x, wave = tid >> 6, lane = tid & 63;
  const int bx = blockIdx.x, hb = bx >> 4, cc = bx & 15, s0 = cc * CH;
  const int h = hb >> 2, b = hb & 3;

  {
    const u16* qg = qb + ((size_t)(hb << 10) + s0) * 64;
    const u16* kg = kb + ((size_t)(hb << 10) + s0) * 64;
    const u16* gg = GTb + (size_t)bx * 4096;
#pragma unroll
    for (int j = 0; j < 2; ++j) {
      const int off = j * 2048 + wave * 512;
      gload16(qg + off + lane * 8, Qs + off);
      gload16(kg + off + lane * 8, Kls + off);
      gload16(gg + off + lane * 8, Gs + off);
    }
    const u16* vg = vTb + ((size_t)hb * 64) * 1024 + s0;
#pragma unroll
    for (int j = 0; j < 2; ++j) {
      const int e0 = j * 32 + wave * 8;
      gload16(vg + (size_t)(e0 + (lane >> 3)) * 1024 + (lane & 7) * 8,
              Vs + e0 * 64);
    }
  }
  __syncthreads();

  const bf16x8* Qs8 = reinterpret_cast<const bf16x8*>(Qs);
  const bf16x8* Ks8 = reinterpret_cast<const bf16x8*>(Kls);
  const bf16x8* Vs8 = reinterpret_cast<const bf16x8*>(Vs);
  const bf16x8* Gs8 = reinterpret_cast<const bf16x8*>(Gs);
  const bf16x8* As8 = reinterpret_cast<const bf16x8*>(Astg);

  const int i0 = wave * 16;
  const int l15 = lane & 15, lk = lane >> 4;

  bf16x8 aq[2];
#pragma unroll
  for (int ks = 0; ks < 2; ++ks)
    aq[ks] = Qs8[(i0 + l15) * 8 + ks * 4 + lk];

  f32x4 a[4] = {};
#pragma unroll
  for (int fj = 0; fj < 4; ++fj)
#pragma unroll
    for (int ks = 0; ks < 2; ++ks) {
      bf16x8 bk = Ks8[(fj * 16 + l15) * 8 + ks * 4 + lk];
      a[fj] = __builtin_amdgcn_mfma_f32_16x16x32_bf16(aq[ks], bk, a[fj], 0, 0, 0);
    }

  const float4 kc4 = *reinterpret_cast<const float4*>(Kc + bx * 64 + l15 * 4);
  float z[4];
  const int rbase = lk * 4;
#pragma unroll
  for (int r = 0; r < 4; ++r) {
    const int il = rbase + r;
    float sum = 0.f;
#pragma unroll
    for (int fj = 0; fj < 4; ++fj) {
      const int j = fj * 16 + l15;
      if (j > i0 + il) a[fj][r] = 0.f;
      sum += a[fj][r];
    }
    const uint2 qrow = *reinterpret_cast<const uint2*>(Qs + (i0 + il) * 64 + l15 * 4);
    const u16* qr16 = reinterpret_cast<const u16*>(&qrow);
    sum += bf2f(qr16[0]) * kc4.x + bf2f(qr16[1]) * kc4.y +
           bf2f(qr16[2]) * kc4.z + bf2f(qr16[3]) * kc4.w;
    z[r] = sum;
  }
#pragma unroll
  for (int off = 1; off <= 8; off <<= 1)
#pragma unroll
    for (int r = 0; r < 4; ++r) z[r] += __shfl_xor(z[r], off);

#pragma unroll
  for (int fj = 0; fj < 4; ++fj)
#pragma unroll
    for (int r = 0; r < 4; ++r)
      Astg[(i0 + rbase + r) * 64 + fj * 16 + l15] = f2bf(a[fj][r]);
  // no barrier: each wave reads only its own 16-row Astg block

  f32x4 o[4] = {};
#pragma unroll
  for (int fe = 0; fe < 4; ++fe) {
#pragma unroll
    for (int ks = 0; ks < 2; ++ks) {
      bf16x8 bg = Gs8[(fe * 16 + l15) * 8 + ks * 4 + lk];
      o[fe] = __builtin_amdgcn_mfma_f32_16x16x32_bf16(aq[ks], bg, o[fe], 0, 0, 0);
    }
#pragma unroll
    for (int ks = 0; ks < 2; ++ks) {
      bf16x8 aa = As8[(i0 + l15) * 8 + ks * 4 + lk];
      bf16x8 bv = Vs8[(fe * 16 + l15) * 8 + ks * 4 + lk];
      o[fe] = __builtin_amdgcn_mfma_f32_16x16x32_bf16(aa, bv, o[fe], 0, 0, 0);
    }
  }

  float rz[4];
#pragma unroll
  for (int r = 0; r < 4; ++r) rz[r] = 1.f / z[r];
#pragma unroll
  for (int fe = 0; fe < 4; ++fe)
#pragma unroll
    for (int r = 0; r < 4; ++r) {
      const int srow = s0 + i0 + rbase + r;
      att[((size_t)(b << 10) + srow) * 512 + h * 64 + fe * 16 + l15] =
          f2bf(o[fe][r] * rz[r]);
    }
}

}  // namespace

extern "C" void kernel_launch(void* const* d_in, const int* in_sizes, int n_in,
                              void* d_out, int out_size, void* d_ws,
                              size_t ws_size, hipStream_t stream) {
  const float* X  = (const float*)d_in[0];
  const float* Wq = (const float*)d_in[2];
  const float* Wk = (const float*)d_in[3];
  const float* Wv = (const float*)d_in[4];
  const float* Wo = (const float*)d_in[5];
  float* out = (float*)d_out;

  u16* Xb  = (u16*)d_ws;            // QSZ u16
  u16* att = Xb;                    // alias: written after Xb fully consumed
  u16* WCT = Xb + QSZ;              // 1536*512
  u16* WoT = WCT + NQKV * M;        // 512*512
  u16* qb  = WoT + M * M;           // QSZ each
  u16* kb  = qb + QSZ;
  u16* kTb = kb + QSZ;
  u16* vTb = kTb + QSZ;
  u16* GTb = vTb + QSZ;             // QSZ
  float* Ks = (float*)(GTb + QSZ);  // 32768 fp32 (exclusive prefixes)

  prep<<<dim3(2304), 256, 0, stream>>>(X, Wq, Wk, Wv, Wo, Xb, WCT, WoT);
  gemm_qkv<<<dim3(BS / 128, NQKV / 128), 512, 0, stream>>>(Xb, WCT, qb, kb,
                                                           kTb, vTb);
  stateprefix<<<dim3(H * B), 256, 0, stream>>>(kTb, vTb, GTb, Ks);
  chunkout_mfma<<<dim3(H * B * NC), 256, 0, stream>>>(qb, kb, vTb, GTb, Ks,
                                                      att);
  gemm_out<<<dim3(BS / 128, M / 64), 512, 0, stream>>>(att, WoT, out);
}

// Round 17
// 51.954 us; speedup vs baseline: 1.2837x; 1.2314x over previous
//
#include <hip/hip_runtime.h>
#include <math.h>

namespace {
typedef unsigned short u16;
typedef __attribute__((ext_vector_type(8))) short bf16x8;
typedef __attribute__((ext_vector_type(4))) float f32x4;

constexpr int H  = 8;
constexpr int B  = 4;
constexpr int S  = 1024;
constexpr int M  = 512;
constexpr int D  = 64;
constexpr int BS = B * S;            // 4096 rows
constexpr int NC = 16;               // chunks per sequence
constexpr int CH = 64;               // chunk length
constexpr int QSZ = H * B * S * D;   // 2097152
constexpr int NQKV = 3 * M;          // 1536

__device__ __forceinline__ float elu1(float x) {
  return x > 0.f ? x + 1.f : __expf(x);
}

__device__ __forceinline__ u16 f2bf(float f) {
  unsigned u = __builtin_bit_cast(unsigned, f);
  u += 0x7fffu + ((u >> 16) & 1u);   // RNE
  return (u16)(u >> 16);
}

__device__ __forceinline__ float bf2f(u16 v) {
  return __builtin_bit_cast(float, ((unsigned)v) << 16);
}

__device__ __forceinline__ void gload16(const u16* g, u16* l) {
  __builtin_amdgcn_global_load_lds(
      (const __attribute__((address_space(1))) unsigned int*)g,
      (__attribute__((address_space(3))) unsigned int*)l, 16, 0, 0);
}

// ---------------------------------------------------------------------------
// prep: fused  convert_x (blocks 0..2047) | build_wqkv (2048..2239) |
//              build_wo (2240..2303)
// ---------------------------------------------------------------------------
__global__ __launch_bounds__(256) void prep(
    const float* __restrict__ X, const float* __restrict__ Wq,
    const float* __restrict__ Wk, const float* __restrict__ Wv,
    const float* __restrict__ Wo, u16* __restrict__ Xb,
    u16* __restrict__ WCT, u16* __restrict__ WoT) {
  __shared__ float t[64][65];
  const int bid = blockIdx.x;
  if (bid < 2048) {
    const int i = bid * 256 + threadIdx.x;
    const float4 v = reinterpret_cast<const float4*>(X)[i];
    u16 o[4] = {f2bf(v.x), f2bf(v.y), f2bf(v.z), f2bf(v.w)};
    *reinterpret_cast<uint2*>(Xb + i * 4) = *reinterpret_cast<uint2*>(o);
  } else if (bid < 2240) {
    const int bb = bid - 2048;
    const int mt = bb & 7, ph = bb >> 3;
    const int p = ph >> 3, h = ph & 7;
    const float* W = ((p == 0) ? Wq : (p == 1) ? Wk : Wv) + h * (M * D);
    const int m0 = mt * 64;
#pragma unroll
    for (int j = 0; j < 4; ++j) {
      const int i = j * 256 + threadIdx.x;
      const int mm = i >> 4, dd = (i & 15) * 4;
      const float4 v = *reinterpret_cast<const float4*>(W + (m0 + mm) * D + dd);
      t[mm][dd + 0] = v.x; t[mm][dd + 1] = v.y;
      t[mm][dd + 2] = v.z; t[mm][dd + 3] = v.w;
    }
    __syncthreads();
    const int dd = threadIdx.x >> 2, qr = (threadIdx.x & 3) * 16;
    u16* o = WCT + (p * M + h * D + dd) * M + m0 + qr;
#pragma unroll
    for (int i = 0; i < 16; ++i) o[i] = f2bf(t[qr + i][dd]);
  } else {
    const int bb = bid - 2240;
    const int m0 = (bb & 7) * 64, n0 = (bb >> 3) * 64;
#pragma unroll
    for (int j = 0; j < 4; ++j) {
      const int i = j * 256 + threadIdx.x;
      const int mm = i >> 4, nn = (i & 15) * 4;
      const float4 v = *reinterpret_cast<const float4*>(Wo + (m0 + mm) * M + n0 + nn);
      t[mm][nn + 0] = v.x; t[mm][nn + 1] = v.y;
      t[mm][nn + 2] = v.z; t[mm][nn + 3] = v.w;
    }
    __syncthreads();
    const int nn = threadIdx.x >> 2, qr = (threadIdx.x & 3) * 16;
    u16* o = WoT + (n0 + nn) * M + m0 + qr;
#pragma unroll
    for (int i = 0; i < 16; ++i) o[i] = f2bf(t[qr + i][nn]);
  }
}

// ---------------------------------------------------------------------------
// QKV GEMM: 128x128 tile, BK=32, dbuf prefetch, 8 waves.
// ---------------------------------------------------------------------------
__global__ __launch_bounds__(512) void gemm_qkv(const u16* __restrict__ A,
                                                const u16* __restrict__ BT,
                                                u16* __restrict__ qb,
                                                u16* __restrict__ kb,
                                                u16* __restrict__ kTb,
                                                u16* __restrict__ vTb) {
  __shared__ alignas(16) u16 As[2][4096];
  __shared__ alignas(16) u16 Bs[2][4096];
  const int tid = threadIdx.x;
  const int wave = tid >> 6, lane = tid & 63;
  const int r0 = blockIdx.x * 128, c0 = blockIdx.y * 128;
  const int wr = (wave >> 1) * 32, wc = (wave & 1) * 64;
  const int l15 = lane & 15, lk = lane >> 4;

  f32x4 acc[2][4] = {};
  const u16* gA = A + (size_t)(r0 + wave * 16 + (lane >> 2)) * 512 + (lane & 3) * 8;
  const u16* gB = BT + (size_t)(c0 + wave * 16 + (lane >> 2)) * 512 + (lane & 3) * 8;

#define STG_QKV(kt, b)                          \
  {                                             \
    const int ko = (kt) * 32;                   \
    gload16(gA + ko, &As[b][wave * 512]);       \
    gload16(gB + ko, &Bs[b][wave * 512]);       \
  }

  STG_QKV(0, 0);
  __syncthreads();
  for (int kt = 0; kt < 16; ++kt) {
    if (kt < 15) STG_QKV(kt + 1, (kt + 1) & 1);
    const bf16x8* As8 = reinterpret_cast<const bf16x8*>(As[kt & 1]);
    const bf16x8* Bs8 = reinterpret_cast<const bf16x8*>(Bs[kt & 1]);
    bf16x8 af[2], bff[4];
#pragma unroll
    for (int mf = 0; mf < 2; ++mf)
      af[mf] = As8[(wr + mf * 16 + l15) * 4 + lk];
#pragma unroll
    for (int nf = 0; nf < 4; ++nf)
      bff[nf] = Bs8[(wc + nf * 16 + l15) * 4 + lk];
#pragma unroll
    for (int mf = 0; mf < 2; ++mf)
#pragma unroll
      for (int nf = 0; nf < 4; ++nf)
        acc[mf][nf] = __builtin_amdgcn_mfma_f32_16x16x32_bf16(
            af[mf], bff[nf], acc[mf][nf], 0, 0, 0);
    __syncthreads();
  }
#undef STG_QKV

#pragma unroll
  for (int nf = 0; nf < 4; ++nf) {
    const int col = c0 + wc + nf * 16 + l15;
    const int p = col >> 9, hh = (col >> 6) & 7, dd = col & 63;
#pragma unroll
    for (int mf = 0; mf < 2; ++mf) {
      const int rowb = r0 + wr + mf * 16 + lk * 4;
      const int b = rowb >> 10, s = rowb & 1023;
      const int hb = hh * B + b;
      u16 ov[4];
#pragma unroll
      for (int r = 0; r < 4; ++r) {
        float v = acc[mf][nf][r];
        if (p < 2) v = elu1(v);
        ov[r] = f2bf(v);
      }
      if (p == 0) {
#pragma unroll
        for (int r = 0; r < 4; ++r)
          qb[((size_t)(hb << 10) + s + r) * 64 + dd] = ov[r];
      } else if (p == 1) {
#pragma unroll
        for (int r = 0; r < 4; ++r)
          kb[((size_t)(hb << 10) + s + r) * 64 + dd] = ov[r];
        *reinterpret_cast<uint2*>(kTb + ((size_t)(hb * 64 + dd) << 10) + s) =
            *reinterpret_cast<uint2*>(ov);
      } else {
        *reinterpret_cast<uint2*>(vTb + ((size_t)(hb * 64 + dd) << 10) + s) =
            *reinterpret_cast<uint2*>(ov);
      }
    }
  }
}

// ---------------------------------------------------------------------------
// Output GEMM: 128x64 tile, BK=32, dbuf prefetch, 8 waves.
// ---------------------------------------------------------------------------
__global__ __launch_bounds__(512) void gemm_out(const u16* __restrict__ A,
                                                const u16* __restrict__ BT,
                                                float* __restrict__ out) {
  __shared__ alignas(16) u16 As[2][4096];
  __shared__ alignas(16) u16 Bs[2][2048];
  const int tid = threadIdx.x;
  const int wave = tid >> 6, lane = tid & 63;
  const int r0 = blockIdx.x * 128, c0 = blockIdx.y * 64;
  const int wr = (wave >> 1) * 32, wc = (wave & 1) * 32;
  const int l15 = lane & 15, lk = lane >> 4;

  f32x4 acc[2][2] = {};
  const u16* gA = A + (size_t)(r0 + wave * 16 + (lane >> 2)) * 512 + (lane & 3) * 8;
  const u16* gB = BT + (size_t)(c0 + (wave - 4) * 16 + (lane >> 2)) * 512 + (lane & 3) * 8;

#define STG_OUT(kt, b)                                        \
  {                                                           \
    const int ko = (kt) * 32;                                 \
    gload16(gA + ko, &As[b][wave * 512]);                     \
    if (wave >= 4) gload16(gB + ko, &Bs[b][(wave - 4) * 512]); \
  }

  STG_OUT(0, 0);
  __syncthreads();
  for (int kt = 0; kt < 16; ++kt) {
    if (kt < 15) STG_OUT(kt + 1, (kt + 1) & 1);
    const bf16x8* As8 = reinterpret_cast<const bf16x8*>(As[kt & 1]);
    const bf16x8* Bs8 = reinterpret_cast<const bf16x8*>(Bs[kt & 1]);
    bf16x8 a[2], b[2];
#pragma unroll
    for (int mf = 0; mf < 2; ++mf)
      a[mf] = As8[(wr + mf * 16 + l15) * 4 + lk];
#pragma unroll
    for (int nf = 0; nf < 2; ++nf)
      b[nf] = Bs8[(wc + nf * 16 + l15) * 4 + lk];
#pragma unroll
    for (int mf = 0; mf < 2; ++mf)
#pragma unroll
      for (int nf = 0; nf < 2; ++nf)
        acc[mf][nf] = __builtin_amdgcn_mfma_f32_16x16x32_bf16(
            a[mf], b[nf], acc[mf][nf], 0, 0, 0);
    __syncthreads();
  }
#undef STG_OUT

#pragma unroll
  for (int nf = 0; nf < 2; ++nf) {
    const int col = c0 + wc + nf * 16 + l15;
#pragma unroll
    for (int mf = 0; mf < 2; ++mf)
#pragma unroll
      for (int r = 0; r < 4; ++r) {
        const int row = r0 + wr + mf * 16 + lk * 4 + r;
        out[(size_t)row * M + col] = acc[mf][nf][r];
      }
  }
}

// ---------------------------------------------------------------------------
// Chunk Gram state via MFMA.
// ---------------------------------------------------------------------------
__global__ __launch_bounds__(256) void chunkstate_mfma(
    const u16* __restrict__ kTb, const u16* __restrict__ vTb,
    float* __restrict__ G32, float* __restrict__ Ks) {
  const int tid = threadIdx.x, wave = tid >> 6, lane = tid & 63;
  const int bx = blockIdx.x, hb = bx >> 4, cc = bx & 15, s0 = cc * CH;
  const u16* vbase = vTb + ((size_t)hb * 64) * 1024 + s0;
  const u16* kbase = kTb + ((size_t)hb * 64) * 1024 + s0;

  bf16x8 av[2];
#pragma unroll
  for (int ks = 0; ks < 2; ++ks)
    av[ks] = *reinterpret_cast<const bf16x8*>(
        vbase + (size_t)(wave * 16 + (lane & 15)) * 1024 + ks * 32 + (lane >> 4) * 8);

  f32x4 acc[4] = {};
#pragma unroll
  for (int fd = 0; fd < 4; ++fd)
#pragma unroll
    for (int ks = 0; ks < 2; ++ks) {
      bf16x8 bk = *reinterpret_cast<const bf16x8*>(
          kbase + (size_t)(fd * 16 + (lane & 15)) * 1024 + ks * 32 + (lane >> 4) * 8);
      acc[fd] = __builtin_amdgcn_mfma_f32_16x16x32_bf16(av[ks], bk, acc[fd], 0, 0, 0);
    }

  float* Gp = G32 + (size_t)bx * 4096;
#pragma unroll
  for (int fd = 0; fd < 4; ++fd)
#pragma unroll
    for (int r = 0; r < 4; ++r) {
      const int e = wave * 16 + (lane >> 4) * 4 + r;
      const int d = fd * 16 + (lane & 15);
      Gp[e * 64 + d] = acc[fd][r];
    }

  const int d = tid >> 2, tq = tid & 3;
  const u16* kp = kbase + (size_t)d * 1024 + tq * 16;
  float ks = 0.f;
#pragma unroll
  for (int j = 0; j < 16; ++j) ks += bf2f(kp[j]);
  ks += __shfl_xor(ks, 1);
  ks += __shfl_xor(ks, 2);
  if (tq == 0) Ks[bx * 64 + d] = ks;
}

// ---------------------------------------------------------------------------
// Exclusive prefix over chunks.
// ---------------------------------------------------------------------------
__global__ __launch_bounds__(256) void prefix_kernel(
    const float* __restrict__ G32, u16* __restrict__ GTb,
    float* __restrict__ Ks) {
  const int hb = blockIdx.x, eg = blockIdx.y;
  const int tid = threadIdx.x;
  const int e = eg * 4 + (tid >> 6), d = tid & 63;
  const size_t base = ((size_t)(hb * 16) * 64 + e) * 64 + d;
  float acc = 0.f;
#pragma unroll
  for (int c = 0; c < 16; ++c) {
    const float v = G32[base + (size_t)c * 4096];
    GTb[base + (size_t)c * 4096] = f2bf(acc);
    acc += v;
  }
  if (eg == 0 && tid < 64) {
    float ka = 0.f;
#pragma unroll
    for (int c = 0; c < 16; ++c) {
      const int idx = (hb * 16 + c) * 64 + tid;
      const float v = Ks[idx];
      Ks[idx] = ka;
      ka += v;
    }
  }
}

// ---------------------------------------------------------------------------
// Chunk output via MFMA:  O = Q·G_prev + tril(Q K^T)·V ;  Z = Q·kc + rowsum.
// ---------------------------------------------------------------------------
__global__ __launch_bounds__(256) void chunkout_mfma(
    const u16* __restrict__ qb, const u16* __restrict__ kb,
    const u16* __restrict__ vTb, const u16* __restrict__ GTb,
    const float* __restrict__ Kc, u16* __restrict__ att) {
  __shared__ alignas(16) u16 Qs[4096], Kls[4096], Vs[4096], Gs[4096], Astg[4096];
  const int tid = threadIdx.x, wave = tid >> 6, lane = tid & 63;
  const int bx = blockIdx.x, hb = bx >> 4, cc = bx & 15, s0 = cc * CH;
  const int h = hb >> 2, b = hb & 3;

  {
    const u16* qg = qb + ((size_t)(hb << 10) + s0) * 64;
    const u16* kg = kb + ((size_t)(hb << 10) + s0) * 64;
    const u16* gg = GTb + (size_t)bx * 4096;
#pragma unroll
    for (int j = 0; j < 2; ++j) {
      const int off = j * 2048 + wave * 512;
      gload16(qg + off + lane * 8, Qs + off);
      gload16(kg + off + lane * 8, Kls + off);
      gload16(gg + off + lane * 8, Gs + off);
    }
    const u16* vg = vTb + ((size_t)hb * 64) * 1024 + s0;
#pragma unroll
    for (int j = 0; j < 2; ++j) {
      const int e0 = j * 32 + wave * 8;
      gload16(vg + (size_t)(e0 + (lane >> 3)) * 1024 + (lane & 7) * 8,
              Vs + e0 * 64);
    }
  }
  __syncthreads();

  const bf16x8* Qs8 = reinterpret_cast<const bf16x8*>(Qs);
  const bf16x8* Ks8 = reinterpret_cast<const bf16x8*>(Kls);
  const bf16x8* Vs8 = reinterpret_cast<const bf16x8*>(Vs);
  const bf16x8* Gs8 = reinterpret_cast<const bf16x8*>(Gs);
  const bf16x8* As8 = reinterpret_cast<const bf16x8*>(Astg);

  const int i0 = wave * 16;
  const int l15 = lane & 15, lk = lane >> 4;

  bf16x8 aq[2];
#pragma unroll
  for (int ks = 0; ks < 2; ++ks)
    aq[ks] = Qs8[(i0 + l15) * 8 + ks * 4 + lk];

  f32x4 a[4] = {};
#pragma unroll
  for (int fj = 0; fj < 4; ++fj)
#pragma unroll
    for (int ks = 0; ks < 2; ++ks) {
      bf16x8 bk = Ks8[(fj * 16 + l15) * 8 + ks * 4 + lk];
      a[fj] = __builtin_amdgcn_mfma_f32_16x16x32_bf16(aq[ks], bk, a[fj], 0, 0, 0);
    }

  const float4 kc4 = *reinterpret_cast<const float4*>(Kc + bx * 64 + l15 * 4);
  float z[4];
  const int rbase = lk * 4;
#pragma unroll
  for (int r = 0; r < 4; ++r) {
    const int il = rbase + r;
    float sum = 0.f;
#pragma unroll
    for (int fj = 0; fj < 4; ++fj) {
      const int j = fj * 16 + l15;
      if (j > i0 + il) a[fj][r] = 0.f;
      sum += a[fj][r];
    }
    const uint2 qrow = *reinterpret_cast<const uint2*>(Qs + (i0 + il) * 64 + l15 * 4);
    const u16* qr16 = reinterpret_cast<const u16*>(&qrow);
    sum += bf2f(qr16[0]) * kc4.x + bf2f(qr16[1]) * kc4.y +
           bf2f(qr16[2]) * kc4.z + bf2f(qr16[3]) * kc4.w;
    z[r] = sum;
  }
#pragma unroll
  for (int off = 1; off <= 8; off <<= 1)
#pragma unroll
    for (int r = 0; r < 4; ++r) z[r] += __shfl_xor(z[r], off);

#pragma unroll
  for (int fj = 0; fj < 4; ++fj)
#pragma unroll
    for (int r = 0; r < 4; ++r)
      Astg[(i0 + rbase + r) * 64 + fj * 16 + l15] = f2bf(a[fj][r]);
  // no barrier: each wave reads only its own 16-row Astg block

  f32x4 o[4] = {};
#pragma unroll
  for (int fe = 0; fe < 4; ++fe) {
#pragma unroll
    for (int ks = 0; ks < 2; ++ks) {
      bf16x8 bg = Gs8[(fe * 16 + l15) * 8 + ks * 4 + lk];
      o[fe] = __builtin_amdgcn_mfma_f32_16x16x32_bf16(aq[ks], bg, o[fe], 0, 0, 0);
    }
#pragma unroll
    for (int ks = 0; ks < 2; ++ks) {
      bf16x8 aa = As8[(i0 + l15) * 8 + ks * 4 + lk];
      bf16x8 bv = Vs8[(fe * 16 + l15) * 8 + ks * 4 + lk];
      o[fe] = __builtin_amdgcn_mfma_f32_16x16x32_bf16(aa, bv, o[fe], 0, 0, 0);
    }
  }

  float rz[4];
#pragma unroll
  for (int r = 0; r < 4; ++r) rz[r] = 1.f / z[r];
#pragma unroll
  for (int fe = 0; fe < 4; ++fe)
#pragma unroll
    for (int r = 0; r < 4; ++r) {
      const int srow = s0 + i0 + rbase + r;
      att[((size_t)(b << 10) + srow) * 512 + h * 64 + fe * 16 + l15] =
          f2bf(o[fe][r] * rz[r]);
    }
}

}  // namespace

extern "C" void kernel_launch(void* const* d_in, const int* in_sizes, int n_in,
                              void* d_out, int out_size, void* d_ws,
                              size_t ws_size, hipStream_t stream) {
  const float* X  = (const float*)d_in[0];
  const float* Wq = (const float*)d_in[2];
  const float* Wk = (const float*)d_in[3];
  const float* Wv = (const float*)d_in[4];
  const float* Wo = (const float*)d_in[5];
  float* out = (float*)d_out;

  u16* Xb  = (u16*)d_ws;            // QSZ u16
  u16* att = Xb;                    // alias: written after Xb fully consumed
  u16* WCT = Xb + QSZ;              // 1536*512
  u16* WoT = WCT + NQKV * M;        // 512*512
  u16* qb  = WoT + M * M;           // QSZ each
  u16* kb  = qb + QSZ;
  u16* kTb = kb + QSZ;
  u16* vTb = kTb + QSZ;
  u16* GTb = vTb + QSZ;             // QSZ
  float* G32 = (float*)(GTb + QSZ); // QSZ fp32
  float* Ks  = G32 + QSZ;           // 32768 fp32

  prep<<<dim3(2304), 256, 0, stream>>>(X, Wq, Wk, Wv, Wo, Xb, WCT, WoT);
  gemm_qkv<<<dim3(BS / 128, NQKV / 128), 512, 0, stream>>>(Xb, WCT, qb, kb,
                                                           kTb, vTb);
  chunkstate_mfma<<<dim3(H * B * NC), 256, 0, stream>>>(kTb, vTb, G32, Ks);
  prefix_kernel<<<dim3(H * B, 16), 256, 0, stream>>>(G32, GTb, Ks);
  chunkout_mfma<<<dim3(H * B * NC), 256, 0, stream>>>(qb, kb, vTb, GTb, Ks,
                                                      att);
  gemm_out<<<dim3(BS / 128, M / 64), 512, 0, stream>>>(att, WoT, out);
}